// Round 13
// baseline (583.005 us; speedup 1.0000x reference)
//
#include <hip/hip_runtime.h>
#include <hip/hip_bf16.h>
#include <stdint.h>

typedef __bf16 bf16;
typedef bf16 bf16x8 __attribute__((ext_vector_type(8)));
typedef bf16 bf16x4 __attribute__((ext_vector_type(4)));
typedef float f32x4 __attribute__((ext_vector_type(4)));

#define NQ_    8
#define EMBED_ 1024
#define FFN_   4096
#define MROWS  32768   // B*S = 8*4096
#define NOUT   1024    // EMBED
#define NT_    (FFN_ / 64)   // 64 K-tiles of BK=64

// ---- async global->LDS, 16B per lane, wave-uniform LDS base ----
__device__ __forceinline__ void gl_lds16(const bf16* g, bf16* l) {
  __builtin_amdgcn_global_load_lds(
      (__attribute__((address_space(1))) void*)(const_cast<bf16*>(g)),
      (__attribute__((address_space(3))) void*)l, 16, 0, 0);
}

#define BAR()   __builtin_amdgcn_s_barrier()
#define VM2()   asm volatile("s_waitcnt vmcnt(2)" ::: "memory")
#define VM0()   asm volatile("s_waitcnt vmcnt(0)" ::: "memory")
#define MFMA(a, b, c) __builtin_amdgcn_mfma_f32_16x16x32_bf16((a), (b), (c), 0, 0, 0)

// ============================================================
// Kernel 1: W_out f32 -> bf16
// ============================================================
__global__ __launch_bounds__(256) void k_wcvt(const float* __restrict__ w,
                                              bf16* __restrict__ wb) {
  const int i = (blockIdx.x * 256 + threadIdx.x) * 4;
  const float4 v = *(const float4*)(w + i);
  bf16x4 o;
  o[0] = (bf16)v.x; o[1] = (bf16)v.y; o[2] = (bf16)v.z; o[3] = (bf16)v.w;
  *(bf16x4*)(wb + i) = o;
}

// ============================================================
// Kernel 2 (FUSED encode+hgen): per block, 16 rows:
//   theta = x @ Wenc^T ; z = analytic circuit expvals (in LDS)
//   h[r][:] = relu(z[r] @ Wdec^T) -> bf16
//   z_0 = prod_{w=1..7} cos(th_w); z_k = prod_{w=0..k} cos(th_w)
// ============================================================
__global__ __launch_bounds__(256) void k_fused(const float* __restrict__ x,
                                               const float* __restrict__ Wenc,
                                               const float* __restrict__ Wdec,
                                               bf16* __restrict__ h,
                                               int row0) {
  const int t = threadIdx.x;
  const int wave = t >> 6, lane = t & 63;
  const int l0 = blockIdx.x * 16;        // local chunk row base
  const int r0 = row0 + l0;              // global row base

  float4 we[8];
#pragma unroll
  for (int q = 0; q < 8; ++q)
    we[q] = *(const float4*)(Wenc + q * EMBED_ + t * 4);

  __shared__ float red[16][4][8];
  __shared__ float cb[16][8];
  __shared__ float zs[16][8];

  for (int rr = 0; rr < 16; ++rr) {
    const float4 xv = *(const float4*)(x + (size_t)(r0 + rr) * EMBED_ + t * 4);
#pragma unroll
    for (int q = 0; q < 8; ++q) {
      float v = xv.x * we[q].x + xv.y * we[q].y + xv.z * we[q].z + xv.w * we[q].w;
#pragma unroll
      for (int off = 32; off > 0; off >>= 1) v += __shfl_xor(v, off, 64);
      if (lane == 0) red[rr][wave][q] = v;
    }
  }
  __syncthreads();
  if (t < 128) {
    const int rr = t >> 3, q = t & 7;
    const float th = red[rr][0][q] + red[rr][1][q] + red[rr][2][q] + red[rr][3][q];
    cb[rr][q] = cosf(th);
  }
  __syncthreads();
  if (t < 16) {
    float c[8];
#pragma unroll
    for (int q = 0; q < 8; ++q) c[q] = cb[t][q];
    zs[t][0] = c[1] * c[2] * c[3] * c[4] * c[5] * c[6] * c[7];
    float p = c[0];
#pragma unroll
    for (int k = 1; k < 8; ++k) { p *= c[k]; zs[t][k] = p; }
  }
  __syncthreads();

  // hgen for these 16 rows: two f-halves of 2048, thread owns 8 f each
#pragma unroll
  for (int half = 0; half < 2; ++half) {
    const int f0 = half * 2048 + t * 8;
    float4 wd[16];
#pragma unroll
    for (int i = 0; i < 16; ++i)
      wd[i] = *(const float4*)(Wdec + (size_t)f0 * 8 + i * 4);
    for (int rr = 0; rr < 16; ++rr) {
      const float4 z0 = *(const float4*)(&zs[rr][0]);
      const float4 z1 = *(const float4*)(&zs[rr][4]);
      bf16x8 o;
#pragma unroll
      for (int j = 0; j < 8; ++j) {
        const float4 a = wd[j * 2], b = wd[j * 2 + 1];
        float s = a.x * z0.x + a.y * z0.y + a.z * z0.z + a.w * z0.w +
                  b.x * z1.x + b.y * z1.y + b.z * z1.z + b.w * z1.w;
        o[j] = (bf16)fmaxf(s, 0.0f);
      }
      *(bf16x8*)(h + (size_t)(l0 + rr) * FFN_ + f0) = o;
    }
  }
}

// ============================================================
// Kernel 3: out = h @ W_out^T — r11 4-barrier schedule +
// issue-order == consumption-order: reads interleaved (a[m],b[m])
// kk-major; MFMA loops kk-outer so first MFMA waits on 2 reads not 9.
// Per-acc K order unchanged (k0 then k1 per (m,n)) -> bitwise identical.
//   ph1: reads a1+b interleaved | stage B01(T+1)->cn | Q0 | BAR
//   ph2:                        | stage B23,A23(T+1)->cn | Q1 | BAR
//   ph3: reads a2(8)            |                        | Q2 | BAR
//   ph4:                        | stage A01(T+2)->c | Q3 | VM2 | BAR
// (r12 lesson: 2-barrier merge hurts; r6/r10: no cross-phase prefetch/fusion)
// ============================================================
__global__ __launch_bounds__(512, 2) void k_gemm8(const bf16* __restrict__ A,
                                                  const bf16* __restrict__ Bt,
                                                  float* __restrict__ C,
                                                  int row0) {
  __shared__ bf16 lds[65536];  // 128 KiB: buf c at c*32768 = [A 16384 | B 16384]

  // bijective XCD swizzle (m204)
  const int nwg = (int)gridDim.x, orig = (int)blockIdx.x;
  const int qd = nwg >> 3, rm = nwg & 7;
  const int xcd = orig & 7;
  const int bid = (xcd < rm ? xcd * (qd + 1) : rm * (qd + 1) + (xcd - rm) * qd) + (orig >> 3);
  const int mi = bid >> 2, ni = bid & 3;

  const int t = threadIdx.x;
  const int wave = t >> 6, lane = t & 63;
  const int wm = wave >> 2, wn = wave & 3;

  // staging geometry: thread t covers row qrow0 (+64s), pre-swizzled slot qc8
  const int qrow0 = t >> 3;
  const int qc8 = (t & 7) ^ (qrow0 & 7);
  const int wbase = wave * 512;            // wave-uniform LDS base (1024 B/wave)

  // 8 persistent global pointers (advanced += 64 elems per K-tile)
  const bf16* gA = A + (size_t)(mi * 256 + qrow0) * FFN_ + qc8 * 8;
  const bf16* gB = Bt + (size_t)(ni * 256 + qrow0) * FFN_ + qc8 * 8;
  const bf16* pA0 = gA;
  const bf16* pA1 = gA + (size_t)64 * FFN_;
  const bf16* pA2 = gA + (size_t)128 * FFN_;
  const bf16* pA3 = gA + (size_t)192 * FFN_;
  const bf16* pB0 = gB;
  const bf16* pB1 = gB + (size_t)64 * FFN_;
  const bf16* pB2 = gB + (size_t)128 * FFN_;
  const bf16* pB3 = gB + (size_t)192 * FFN_;

#define STAGE(p0, p1, roff, ahead, cc)                                          \
  do {                                                                          \
    gl_lds16((p0) + (ahead) * 64, (bf16*)lds + (cc) * 32768 + (roff) + wbase);  \
    gl_lds16((p1) + (ahead) * 64,                                               \
             (bf16*)lds + (cc) * 32768 + (roff) + 4096 + wbase);                \
  } while (0)

  // flattened per-lane ds_read bases (r7, elems)
  const int fr = lane & 15, fk = (lane >> 4) * 8;
  const int swz = (fr & 7) << 3;
  const int a0 = (wm * 128 + fr) * 64 + (fk ^ swz);
  const int a1 = a0 ^ 32;
  const int b0 = 16384 + (wn * 64 + fr) * 64 + (fk ^ swz);
  const int b1 = b0 ^ 32;

  auto ldA = [&](int c, int m, int kk) -> bf16x8 {
    return *(const bf16x8*)((const bf16*)lds + c * 32768 + (kk ? a1 : a0) + m * 1024);
  };
  auto ldB = [&](int c, int n, int kk) -> bf16x8 {
    return *(const bf16x8*)((const bf16*)lds + c * 32768 + (kk ? b1 : b0) + n * 1024);
  };

  f32x4 acc[8][4] = {};

  // prologue: tile0 fully (c=0) + A01 of tile1 (c=1); VM2 keeps A01(1)
  STAGE(pA0, pA1, 0, 0, 0);
  STAGE(pA2, pA3, 8192, 0, 0);
  STAGE(pB0, pB1, 16384, 0, 0);
  STAGE(pB2, pB3, 24576, 0, 0);
  STAGE(pA0, pA1, 0, 1, 1);
  VM2();
  BAR();

#pragma unroll 2
  for (int T = 0; T < NT_; ++T) {
    const int c = T & 1, cn = c ^ 1;
    bf16x8 a1r[4][2], a2r[4][2], br[4][2];

    // ---- phase 1: reads a1+b interleaved; stage B01(T+1)->cn; Q0; BAR ----
#pragma unroll
    for (int m = 0; m < 4; ++m) { a1r[m][0] = ldA(c, m, 0); br[m][0] = ldB(c, m, 0); }
#pragma unroll
    for (int m = 0; m < 4; ++m) { a1r[m][1] = ldA(c, m, 1); br[m][1] = ldB(c, m, 1); }
    if (T + 1 < NT_) STAGE(pB0, pB1, 16384, 1, cn);
    __builtin_amdgcn_s_setprio(1);
#pragma unroll
    for (int kk = 0; kk < 2; ++kk)
#pragma unroll
      for (int m = 0; m < 4; ++m)
#pragma unroll
        for (int n = 0; n < 2; ++n)
          acc[m][n] = MFMA(a1r[m][kk], br[n][kk], acc[m][n]);
    __builtin_amdgcn_s_setprio(0);
    BAR();

    // ---- phase 2: stage B23(T+1),A23(T+1)->cn; Q1; BAR ----
    if (T + 1 < NT_) {
      STAGE(pB2, pB3, 24576, 1, cn);
      STAGE(pA2, pA3, 8192, 1, cn);
    }
    __builtin_amdgcn_s_setprio(1);
#pragma unroll
    for (int kk = 0; kk < 2; ++kk)
#pragma unroll
      for (int m = 0; m < 4; ++m)
#pragma unroll
        for (int n = 2; n < 4; ++n)
          acc[m][n] = MFMA(a1r[m][kk], br[n][kk], acc[m][n]);
    __builtin_amdgcn_s_setprio(0);
    BAR();

    // ---- phase 3: reads a2(8); Q2; BAR ----
#pragma unroll
    for (int m = 0; m < 4; ++m) { a2r[m][0] = ldA(c, m + 4, 0); a2r[m][1] = ldA(c, m + 4, 1); }
    __builtin_amdgcn_s_setprio(1);
#pragma unroll
    for (int kk = 0; kk < 2; ++kk)
#pragma unroll
      for (int m = 0; m < 4; ++m)
#pragma unroll
        for (int n = 0; n < 2; ++n)
          acc[m + 4][n] = MFMA(a2r[m][kk], br[n][kk], acc[m + 4][n]);
    __builtin_amdgcn_s_setprio(0);
    BAR();

    // ---- phase 4: stage A01(T+2)->c; Q3; VM2; BAR ----
    if (T + 2 < NT_) STAGE(pA0, pA1, 0, 2, c);
    __builtin_amdgcn_s_setprio(1);
#pragma unroll
    for (int kk = 0; kk < 2; ++kk)
#pragma unroll
      for (int m = 0; m < 4; ++m)
#pragma unroll
        for (int n = 2; n < 4; ++n)
          acc[m + 4][n] = MFMA(a2r[m][kk], br[n][kk], acc[m + 4][n]);
    __builtin_amdgcn_s_setprio(0);
    if (T < NT_ - 2) { VM2(); } else { VM0(); }
    BAR();

    pA0 += 64; pA1 += 64; pA2 += 64; pA3 += 64;
    pB0 += 64; pB1 += 64; pB2 += 64; pB3 += 64;
  }
#undef STAGE

  // epilogue: C/D layout col=lane&15, row=(lane>>4)*4+j (m89/m91)
  const int orow = (lane >> 4) * 4, ocol = lane & 15;
  const int rbase = row0 + mi * 256 + wm * 128;
  const int cbase = ni * 256 + wn * 64;
#pragma unroll
  for (int m = 0; m < 8; ++m)
#pragma unroll
    for (int n = 0; n < 4; ++n)
#pragma unroll
      for (int j = 0; j < 4; ++j)
        C[(size_t)(rbase + m * 16 + orow + j) * NOUT + (cbase + n * 16 + ocol)] =
            acc[m][n][j];
}

// ============================================================
extern "C" void kernel_launch(void* const* d_in, const int* in_sizes, int n_in,
                              void* d_out, int out_size, void* d_ws, size_t ws_size,
                              hipStream_t stream) {
  const float* x    = (const float*)d_in[0];
  const float* Wenc = (const float*)d_in[1];
  const float* Wdec = (const float*)d_in[2];
  const float* Wout = (const float*)d_in[3];
  float* out = (float*)d_out;

  char* ws = (char*)d_ws;
  bf16*  Wb = (bf16*)ws;                   // 8 MiB
  bf16*  h  = (bf16*)(ws + 8388608);       // up to 256 MiB

  const size_t head = 8388608;
  const size_t avail = ws_size > head ? ws_size - head : 0;
  int nch = 1;
  while (nch < 128 && (size_t)(MROWS / nch) * FFN_ * 2 > avail) nch <<= 1;
  const int chunk = MROWS / nch;   // multiple of 256

  k_wcvt<<<4096, 256, 0, stream>>>(Wout, Wb);
  for (int c = 0; c < nch; ++c) {
    const int row0 = c * chunk;
    k_fused<<<chunk / 16, 256, 0, stream>>>(x, Wenc, Wdec, h, row0);
    k_gemm8<<<(chunk / 256) * 4, 512, 0, stream>>>(h, Wb, out, row0);
  }
}

// Round 14
// 363.323 us; speedup vs baseline: 1.6046x; 1.6046x over previous
//
#include <hip/hip_runtime.h>
#include <hip/hip_bf16.h>
#include <stdint.h>

typedef __bf16 bf16;
typedef bf16 bf16x8 __attribute__((ext_vector_type(8)));
typedef bf16 bf16x4 __attribute__((ext_vector_type(4)));
typedef float f32x4 __attribute__((ext_vector_type(4)));

#define NQ_    8
#define EMBED_ 1024
#define FFN_   4096
#define MROWS  32768   // B*S = 8*4096
#define NOUT   1024    // EMBED
#define NT_    (FFN_ / 64)   // 64 K-tiles of BK=64

// ---- async global->LDS, 16B per lane, wave-uniform LDS base ----
__device__ __forceinline__ void gl_lds16(const bf16* g, bf16* l) {
  __builtin_amdgcn_global_load_lds(
      (__attribute__((address_space(1))) void*)(const_cast<bf16*>(g)),
      (__attribute__((address_space(3))) void*)l, 16, 0, 0);
}

#define BAR()   __builtin_amdgcn_s_barrier()
#define VM2()   asm volatile("s_waitcnt vmcnt(2)" ::: "memory")
#define VM0()   asm volatile("s_waitcnt vmcnt(0)" ::: "memory")
#define MFMA(a, b, c) __builtin_amdgcn_mfma_f32_16x16x32_bf16((a), (b), (c), 0, 0, 0)

// ============================================================
// Kernel 1: W_out f32 -> bf16
// ============================================================
__global__ __launch_bounds__(256) void k_wcvt(const float* __restrict__ w,
                                              bf16* __restrict__ wb) {
  const int i = (blockIdx.x * 256 + threadIdx.x) * 4;
  const float4 v = *(const float4*)(w + i);
  bf16x4 o;
  o[0] = (bf16)v.x; o[1] = (bf16)v.y; o[2] = (bf16)v.z; o[3] = (bf16)v.w;
  *(bf16x4*)(wb + i) = o;
}

// ============================================================
// Kernel 2: theta = x @ W_enc^T ; z = analytic circuit expvals
//   z_0 = prod_{w=1..7} cos(theta_w); z_k = prod_{w=0..k} cos(theta_w)
// (r13 lesson: fusing this into hgen tanks occupancy — keep separate)
// ============================================================
__global__ __launch_bounds__(256) void k_encode(const float* __restrict__ x,
                                                const float* __restrict__ Wenc,
                                                float* __restrict__ z) {
  const int t = threadIdx.x;
  const int wave = t >> 6, lane = t & 63;
  const int r0 = blockIdx.x * 16;

  float4 we[8];
#pragma unroll
  for (int q = 0; q < 8; ++q)
    we[q] = *(const float4*)(Wenc + q * EMBED_ + t * 4);

  __shared__ float red[16][4][8];
  __shared__ float cb[16][8];

  for (int rr = 0; rr < 16; ++rr) {
    const float4 xv = *(const float4*)(x + (size_t)(r0 + rr) * EMBED_ + t * 4);
#pragma unroll
    for (int q = 0; q < 8; ++q) {
      float v = xv.x * we[q].x + xv.y * we[q].y + xv.z * we[q].z + xv.w * we[q].w;
#pragma unroll
      for (int off = 32; off > 0; off >>= 1) v += __shfl_xor(v, off, 64);
      if (lane == 0) red[rr][wave][q] = v;
    }
  }
  __syncthreads();
  if (t < 128) {
    const int rr = t >> 3, q = t & 7;
    const float th = red[rr][0][q] + red[rr][1][q] + red[rr][2][q] + red[rr][3][q];
    cb[rr][q] = cosf(th);
  }
  __syncthreads();
  if (t < 16) {
    float c[8];
#pragma unroll
    for (int q = 0; q < 8; ++q) c[q] = cb[t][q];
    float zz[8];
    zz[0] = c[1] * c[2] * c[3] * c[4] * c[5] * c[6] * c[7];
    float p = c[0];
#pragma unroll
    for (int k = 1; k < 8; ++k) { p *= c[k]; zz[k] = p; }
    float4* zp = (float4*)(z + (size_t)(r0 + t) * 8);
    zp[0] = make_float4(zz[0], zz[1], zz[2], zz[3]);
    zp[1] = make_float4(zz[4], zz[5], zz[6], zz[7]);
  }
}

// ============================================================
// Kernel 3: h = relu(z @ W_dec^T) -> bf16 [chunk_rows][4096]
// ============================================================
__global__ __launch_bounds__(256) void k_hgen(const float* __restrict__ z,
                                              const float* __restrict__ Wdec,
                                              bf16* __restrict__ h,
                                              int row0) {
  const int t = threadIdx.x;
  const int f0 = blockIdx.y * 2048 + t * 8;
  const int g0 = row0 + blockIdx.x * 64;
  const int l0 = blockIdx.x * 64;

  float4 wd[16];
#pragma unroll
  for (int i = 0; i < 16; ++i)
    wd[i] = *(const float4*)(Wdec + (size_t)f0 * 8 + i * 4);

  for (int rr = 0; rr < 64; ++rr) {
    const float4* zp = (const float4*)(z + (size_t)(g0 + rr) * 8);
    const float4 z0 = zp[0], z1 = zp[1];
    bf16x8 o;
#pragma unroll
    for (int j = 0; j < 8; ++j) {
      const float4 a = wd[j * 2], b = wd[j * 2 + 1];
      float s = a.x * z0.x + a.y * z0.y + a.z * z0.z + a.w * z0.w +
                b.x * z1.x + b.y * z1.y + b.z * z1.z + b.w * z1.w;
      o[j] = (bf16)fmaxf(s, 0.0f);
    }
    *(bf16x8*)(h + (size_t)(l0 + rr) * FFN_ + f0) = o;
  }
}

// ============================================================
// Kernel 4: out = h @ W_out^T — r11 4-barrier schedule +
// issue-order == consumption-order (r13-proven: gemm ~241 -> ~185us):
// reads interleaved (a[m],b[m]) kk-major; MFMA kk-outer so first MFMA
// waits on 2 reads not 9. Per-acc K order unchanged -> bitwise identical.
//   ph1: reads a1+b interleaved | stage B01(T+1)->cn | Q0 | BAR
//   ph2:                        | stage B23,A23(T+1)->cn | Q1 | BAR
//   ph3: reads a2(8)            |                        | Q2 | BAR
//   ph4:                        | stage A01(T+2)->c | Q3 | VM2 | BAR
// (r12: 2-barrier merge hurts; r6/r10: no cross-phase prefetch/fusion)
// ============================================================
__global__ __launch_bounds__(512, 2) void k_gemm8(const bf16* __restrict__ A,
                                                  const bf16* __restrict__ Bt,
                                                  float* __restrict__ C,
                                                  int row0) {
  __shared__ bf16 lds[65536];  // 128 KiB: buf c at c*32768 = [A 16384 | B 16384]

  // bijective XCD swizzle (m204)
  const int nwg = (int)gridDim.x, orig = (int)blockIdx.x;
  const int qd = nwg >> 3, rm = nwg & 7;
  const int xcd = orig & 7;
  const int bid = (xcd < rm ? xcd * (qd + 1) : rm * (qd + 1) + (xcd - rm) * qd) + (orig >> 3);
  const int mi = bid >> 2, ni = bid & 3;

  const int t = threadIdx.x;
  const int wave = t >> 6, lane = t & 63;
  const int wm = wave >> 2, wn = wave & 3;

  // staging geometry: thread t covers row qrow0 (+64s), pre-swizzled slot qc8
  const int qrow0 = t >> 3;
  const int qc8 = (t & 7) ^ (qrow0 & 7);
  const int wbase = wave * 512;            // wave-uniform LDS base (1024 B/wave)

  // 8 persistent global pointers (advanced += 64 elems per K-tile)
  const bf16* gA = A + (size_t)(mi * 256 + qrow0) * FFN_ + qc8 * 8;
  const bf16* gB = Bt + (size_t)(ni * 256 + qrow0) * FFN_ + qc8 * 8;
  const bf16* pA0 = gA;
  const bf16* pA1 = gA + (size_t)64 * FFN_;
  const bf16* pA2 = gA + (size_t)128 * FFN_;
  const bf16* pA3 = gA + (size_t)192 * FFN_;
  const bf16* pB0 = gB;
  const bf16* pB1 = gB + (size_t)64 * FFN_;
  const bf16* pB2 = gB + (size_t)128 * FFN_;
  const bf16* pB3 = gB + (size_t)192 * FFN_;

#define STAGE(p0, p1, roff, ahead, cc)                                          \
  do {                                                                          \
    gl_lds16((p0) + (ahead) * 64, (bf16*)lds + (cc) * 32768 + (roff) + wbase);  \
    gl_lds16((p1) + (ahead) * 64,                                               \
             (bf16*)lds + (cc) * 32768 + (roff) + 4096 + wbase);                \
  } while (0)

  // flattened per-lane ds_read bases (r7, elems)
  const int fr = lane & 15, fk = (lane >> 4) * 8;
  const int swz = (fr & 7) << 3;
  const int a0 = (wm * 128 + fr) * 64 + (fk ^ swz);
  const int a1 = a0 ^ 32;
  const int b0 = 16384 + (wn * 64 + fr) * 64 + (fk ^ swz);
  const int b1 = b0 ^ 32;

  auto ldA = [&](int c, int m, int kk) -> bf16x8 {
    return *(const bf16x8*)((const bf16*)lds + c * 32768 + (kk ? a1 : a0) + m * 1024);
  };
  auto ldB = [&](int c, int n, int kk) -> bf16x8 {
    return *(const bf16x8*)((const bf16*)lds + c * 32768 + (kk ? b1 : b0) + n * 1024);
  };

  f32x4 acc[8][4] = {};

  // prologue: tile0 fully (c=0) + A01 of tile1 (c=1); VM2 keeps A01(1)
  STAGE(pA0, pA1, 0, 0, 0);
  STAGE(pA2, pA3, 8192, 0, 0);
  STAGE(pB0, pB1, 16384, 0, 0);
  STAGE(pB2, pB3, 24576, 0, 0);
  STAGE(pA0, pA1, 0, 1, 1);
  VM2();
  BAR();

#pragma unroll 2
  for (int T = 0; T < NT_; ++T) {
    const int c = T & 1, cn = c ^ 1;
    bf16x8 a1r[4][2], a2r[4][2], br[4][2];

    // ---- phase 1: reads a1+b interleaved; stage B01(T+1)->cn; Q0; BAR ----
#pragma unroll
    for (int m = 0; m < 4; ++m) { a1r[m][0] = ldA(c, m, 0); br[m][0] = ldB(c, m, 0); }
#pragma unroll
    for (int m = 0; m < 4; ++m) { a1r[m][1] = ldA(c, m, 1); br[m][1] = ldB(c, m, 1); }
    if (T + 1 < NT_) STAGE(pB0, pB1, 16384, 1, cn);
    __builtin_amdgcn_s_setprio(1);
#pragma unroll
    for (int kk = 0; kk < 2; ++kk)
#pragma unroll
      for (int m = 0; m < 4; ++m)
#pragma unroll
        for (int n = 0; n < 2; ++n)
          acc[m][n] = MFMA(a1r[m][kk], br[n][kk], acc[m][n]);
    __builtin_amdgcn_s_setprio(0);
    BAR();

    // ---- phase 2: stage B23(T+1),A23(T+1)->cn; Q1; BAR ----
    if (T + 1 < NT_) {
      STAGE(pB2, pB3, 24576, 1, cn);
      STAGE(pA2, pA3, 8192, 1, cn);
    }
    __builtin_amdgcn_s_setprio(1);
#pragma unroll
    for (int kk = 0; kk < 2; ++kk)
#pragma unroll
      for (int m = 0; m < 4; ++m)
#pragma unroll
        for (int n = 2; n < 4; ++n)
          acc[m][n] = MFMA(a1r[m][kk], br[n][kk], acc[m][n]);
    __builtin_amdgcn_s_setprio(0);
    BAR();

    // ---- phase 3: reads a2(8); Q2; BAR ----
#pragma unroll
    for (int m = 0; m < 4; ++m) { a2r[m][0] = ldA(c, m + 4, 0); a2r[m][1] = ldA(c, m + 4, 1); }
    __builtin_amdgcn_s_setprio(1);
#pragma unroll
    for (int kk = 0; kk < 2; ++kk)
#pragma unroll
      for (int m = 0; m < 4; ++m)
#pragma unroll
        for (int n = 0; n < 2; ++n)
          acc[m + 4][n] = MFMA(a2r[m][kk], br[n][kk], acc[m + 4][n]);
    __builtin_amdgcn_s_setprio(0);
    BAR();

    // ---- phase 4: stage A01(T+2)->c; Q3; VM2; BAR ----
    if (T + 2 < NT_) STAGE(pA0, pA1, 0, 2, c);
    __builtin_amdgcn_s_setprio(1);
#pragma unroll
    for (int kk = 0; kk < 2; ++kk)
#pragma unroll
      for (int m = 0; m < 4; ++m)
#pragma unroll
        for (int n = 2; n < 4; ++n)
          acc[m + 4][n] = MFMA(a2r[m][kk], br[n][kk], acc[m + 4][n]);
    __builtin_amdgcn_s_setprio(0);
    if (T < NT_ - 2) { VM2(); } else { VM0(); }
    BAR();

    pA0 += 64; pA1 += 64; pA2 += 64; pA3 += 64;
    pB0 += 64; pB1 += 64; pB2 += 64; pB3 += 64;
  }
#undef STAGE

  // epilogue: C/D layout col=lane&15, row=(lane>>4)*4+j (m89/m91)
  const int orow = (lane >> 4) * 4, ocol = lane & 15;
  const int rbase = row0 + mi * 256 + wm * 128;
  const int cbase = ni * 256 + wn * 64;
#pragma unroll
  for (int m = 0; m < 8; ++m)
#pragma unroll
    for (int n = 0; n < 4; ++n)
#pragma unroll
      for (int j = 0; j < 4; ++j)
        C[(size_t)(rbase + m * 16 + orow + j) * NOUT + (cbase + n * 16 + ocol)] =
            acc[m][n][j];
}

// ============================================================
extern "C" void kernel_launch(void* const* d_in, const int* in_sizes, int n_in,
                              void* d_out, int out_size, void* d_ws, size_t ws_size,
                              hipStream_t stream) {
  const float* x    = (const float*)d_in[0];
  const float* Wenc = (const float*)d_in[1];
  const float* Wdec = (const float*)d_in[2];
  const float* Wout = (const float*)d_in[3];
  float* out = (float*)d_out;

  char* ws = (char*)d_ws;
  bf16*  Wb = (bf16*)ws;                          // 8 MiB
  float* z  = (float*)(ws + 8388608);             // 1 MiB
  bf16*  h  = (bf16*)(ws + 8388608 + 1048576);    // up to 256 MiB

  const size_t head = 8388608 + 1048576;
  const size_t avail = ws_size > head ? ws_size - head : 0;
  int nch = 1;
  while (nch < 128 && (size_t)(MROWS / nch) * FFN_ * 2 > avail) nch <<= 1;
  const int chunk = MROWS / nch;   // multiple of 256

  k_wcvt<<<4096, 256, 0, stream>>>(Wout, Wb);
  k_encode<<<2048, 256, 0, stream>>>(x, Wenc, z);
  for (int c = 0; c < nch; ++c) {
    const int row0 = c * chunk;
    dim3 hg(chunk / 64, 2);
    k_hgen<<<hg, 256, 0, stream>>>(z, Wdec, h, row0);
    k_gemm8<<<(chunk / 256) * 4, 512, 0, stream>>>(h, Wb, out, row0);
  }
}

// Round 15
// 361.199 us; speedup vs baseline: 1.6141x; 1.0059x over previous
//
#include <hip/hip_runtime.h>
#include <hip/hip_bf16.h>
#include <stdint.h>

typedef __bf16 bf16;
typedef bf16 bf16x8 __attribute__((ext_vector_type(8)));
typedef bf16 bf16x4 __attribute__((ext_vector_type(4)));
typedef float f32x4 __attribute__((ext_vector_type(4)));

#define NQ_    8
#define EMBED_ 1024
#define FFN_   4096
#define MROWS  32768   // B*S = 8*4096
#define NOUT   1024    // EMBED
#define NT_    (FFN_ / 64)   // 64 K-tiles of BK=64

// ---- async global->LDS, 16B per lane, wave-uniform LDS base ----
__device__ __forceinline__ void gl_lds16(const bf16* g, bf16* l) {
  __builtin_amdgcn_global_load_lds(
      (__attribute__((address_space(1))) void*)(const_cast<bf16*>(g)),
      (__attribute__((address_space(3))) void*)l, 16, 0, 0);
}

#define BAR()   __builtin_amdgcn_s_barrier()
#define VM2()   asm volatile("s_waitcnt vmcnt(2)" ::: "memory")
#define VM0()   asm volatile("s_waitcnt vmcnt(0)" ::: "memory")
#define MFMA(a, b, c) __builtin_amdgcn_mfma_f32_16x16x32_bf16((a), (b), (c), 0, 0, 0)

// ============================================================
// Kernel 1 (encode + folded wcvt): 32 rows/block, grid 1024.
//   wcvt: 16 W_out f32->bf16 per thread (4M total)
//   theta = x @ W_enc^T ; z = analytic circuit expvals
//   z_0 = prod_{w=1..7} cos(th_w); z_k = prod_{w=0..k} cos(th_w)
// (r13 lesson: fusing hgen in tanks occupancy — only wcvt folded here)
// ============================================================
__global__ __launch_bounds__(256) void k_encode(const float* __restrict__ x,
                                                const float* __restrict__ Wenc,
                                                float* __restrict__ z,
                                                const float* __restrict__ w,
                                                bf16* __restrict__ wb) {
  const int t = threadIdx.x;
  const int wave = t >> 6, lane = t & 63;
  const int r0 = blockIdx.x * 32;

  // folded wcvt: this block converts 4096 W elems (16/thread)
  {
    const int i = (blockIdx.x * 256 + t) * 16;
#pragma unroll
    for (int j = 0; j < 4; ++j) {
      const float4 v = *(const float4*)(w + i + j * 4);
      bf16x4 o;
      o[0] = (bf16)v.x; o[1] = (bf16)v.y; o[2] = (bf16)v.z; o[3] = (bf16)v.w;
      *(bf16x4*)(wb + i + j * 4) = o;
    }
  }

  float4 we[8];
#pragma unroll
  for (int q = 0; q < 8; ++q)
    we[q] = *(const float4*)(Wenc + q * EMBED_ + t * 4);

  __shared__ float red[32][4][8];
  __shared__ float cb[32][8];

  for (int rr = 0; rr < 32; ++rr) {
    const float4 xv = *(const float4*)(x + (size_t)(r0 + rr) * EMBED_ + t * 4);
#pragma unroll
    for (int q = 0; q < 8; ++q) {
      float v = xv.x * we[q].x + xv.y * we[q].y + xv.z * we[q].z + xv.w * we[q].w;
#pragma unroll
      for (int off = 32; off > 0; off >>= 1) v += __shfl_xor(v, off, 64);
      if (lane == 0) red[rr][wave][q] = v;
    }
  }
  __syncthreads();
  {
    const int rr = t >> 3, q = t & 7;   // all 256 threads busy (32 rows x 8 q)
    const float th = red[rr][0][q] + red[rr][1][q] + red[rr][2][q] + red[rr][3][q];
    cb[rr][q] = cosf(th);
  }
  __syncthreads();
  if (t < 32) {
    float c[8];
#pragma unroll
    for (int q = 0; q < 8; ++q) c[q] = cb[t][q];
    float zz[8];
    zz[0] = c[1] * c[2] * c[3] * c[4] * c[5] * c[6] * c[7];
    float p = c[0];
#pragma unroll
    for (int k = 1; k < 8; ++k) { p *= c[k]; zz[k] = p; }
    float4* zp = (float4*)(z + (size_t)(r0 + t) * 8);
    zp[0] = make_float4(zz[0], zz[1], zz[2], zz[3]);
    zp[1] = make_float4(zz[4], zz[5], zz[6], zz[7]);
  }
}

// ============================================================
// Kernel 2: h = relu(z @ W_dec^T) -> bf16 [chunk_rows][4096]
// (write-BW-bound at ~4.7 TB/s — near floor, left alone)
// ============================================================
__global__ __launch_bounds__(256) void k_hgen(const float* __restrict__ z,
                                              const float* __restrict__ Wdec,
                                              bf16* __restrict__ h,
                                              int row0) {
  const int t = threadIdx.x;
  const int f0 = blockIdx.y * 2048 + t * 8;
  const int g0 = row0 + blockIdx.x * 64;
  const int l0 = blockIdx.x * 64;

  float4 wd[16];
#pragma unroll
  for (int i = 0; i < 16; ++i)
    wd[i] = *(const float4*)(Wdec + (size_t)f0 * 8 + i * 4);

  for (int rr = 0; rr < 64; ++rr) {
    const float4* zp = (const float4*)(z + (size_t)(g0 + rr) * 8);
    const float4 z0 = zp[0], z1 = zp[1];
    bf16x8 o;
#pragma unroll
    for (int j = 0; j < 8; ++j) {
      const float4 a = wd[j * 2], b = wd[j * 2 + 1];
      float s = a.x * z0.x + a.y * z0.y + a.z * z0.z + a.w * z0.w +
                b.x * z1.x + b.y * z1.y + b.z * z1.z + b.w * z1.w;
      o[j] = (bf16)fmaxf(s, 0.0f);
    }
    *(bf16x8*)(h + (size_t)(l0 + rr) * FFN_ + f0) = o;
  }
}

// ============================================================
// Kernel 3: out = h @ W_out^T — r11 4-barrier schedule, VMEM issue
// balanced 2 gl_lds/phase (A23 stage moved ph2->ph3; ledger: prior
// A23(cn) readers retired >=2 barriers earlier; VM2 recount unchanged).
//   ph1: reads a1+b interleaved | stage B01(T+1)->cn | Q0 | BAR
//   ph2:                        | stage B23(T+1)->cn | Q1 | BAR
//   ph3: reads a2(8)            | stage A23(T+1)->cn | Q2 | BAR
//   ph4:                        | stage A01(T+2)->c  | Q3 | VM2 | BAR
// (r12: 2-barrier merge hurts; r6/r10: no cross-phase prefetch/fusion;
//  r14: issue-order cosmetic — compiler sinks reads into MFMA stream)
// ============================================================
__global__ __launch_bounds__(512, 2) void k_gemm8(const bf16* __restrict__ A,
                                                  const bf16* __restrict__ Bt,
                                                  float* __restrict__ C,
                                                  int row0) {
  __shared__ bf16 lds[65536];  // 128 KiB: buf c at c*32768 = [A 16384 | B 16384]

  // bijective XCD swizzle (m204)
  const int nwg = (int)gridDim.x, orig = (int)blockIdx.x;
  const int qd = nwg >> 3, rm = nwg & 7;
  const int xcd = orig & 7;
  const int bid = (xcd < rm ? xcd * (qd + 1) : rm * (qd + 1) + (xcd - rm) * qd) + (orig >> 3);
  const int mi = bid >> 2, ni = bid & 3;

  const int t = threadIdx.x;
  const int wave = t >> 6, lane = t & 63;
  const int wm = wave >> 2, wn = wave & 3;

  // staging geometry: thread t covers row qrow0 (+64s), pre-swizzled slot qc8
  const int qrow0 = t >> 3;
  const int qc8 = (t & 7) ^ (qrow0 & 7);
  const int wbase = wave * 512;            // wave-uniform LDS base (1024 B/wave)

  // 8 persistent global pointers (advanced += 64 elems per K-tile)
  const bf16* gA = A + (size_t)(mi * 256 + qrow0) * FFN_ + qc8 * 8;
  const bf16* gB = Bt + (size_t)(ni * 256 + qrow0) * FFN_ + qc8 * 8;
  const bf16* pA0 = gA;
  const bf16* pA1 = gA + (size_t)64 * FFN_;
  const bf16* pA2 = gA + (size_t)128 * FFN_;
  const bf16* pA3 = gA + (size_t)192 * FFN_;
  const bf16* pB0 = gB;
  const bf16* pB1 = gB + (size_t)64 * FFN_;
  const bf16* pB2 = gB + (size_t)128 * FFN_;
  const bf16* pB3 = gB + (size_t)192 * FFN_;

#define STAGE(p0, p1, roff, ahead, cc)                                          \
  do {                                                                          \
    gl_lds16((p0) + (ahead) * 64, (bf16*)lds + (cc) * 32768 + (roff) + wbase);  \
    gl_lds16((p1) + (ahead) * 64,                                               \
             (bf16*)lds + (cc) * 32768 + (roff) + 4096 + wbase);                \
  } while (0)

  // flattened per-lane ds_read bases (r7, elems)
  const int fr = lane & 15, fk = (lane >> 4) * 8;
  const int swz = (fr & 7) << 3;
  const int a0 = (wm * 128 + fr) * 64 + (fk ^ swz);
  const int a1 = a0 ^ 32;
  const int b0 = 16384 + (wn * 64 + fr) * 64 + (fk ^ swz);
  const int b1 = b0 ^ 32;

  auto ldA = [&](int c, int m, int kk) -> bf16x8 {
    return *(const bf16x8*)((const bf16*)lds + c * 32768 + (kk ? a1 : a0) + m * 1024);
  };
  auto ldB = [&](int c, int n, int kk) -> bf16x8 {
    return *(const bf16x8*)((const bf16*)lds + c * 32768 + (kk ? b1 : b0) + n * 1024);
  };

  f32x4 acc[8][4] = {};

  // prologue: tile0 fully (c=0) + A01 of tile1 (c=1); VM2 keeps A01(1)
  STAGE(pA0, pA1, 0, 0, 0);
  STAGE(pA2, pA3, 8192, 0, 0);
  STAGE(pB0, pB1, 16384, 0, 0);
  STAGE(pB2, pB3, 24576, 0, 0);
  STAGE(pA0, pA1, 0, 1, 1);
  VM2();
  BAR();

#pragma unroll 2
  for (int T = 0; T < NT_; ++T) {
    const int c = T & 1, cn = c ^ 1;
    bf16x8 a1r[4][2], a2r[4][2], br[4][2];

    // ---- phase 1: reads a1+b; stage B01(T+1)->cn; Q0; BAR ----
#pragma unroll
    for (int m = 0; m < 4; ++m) { a1r[m][0] = ldA(c, m, 0); br[m][0] = ldB(c, m, 0); }
#pragma unroll
    for (int m = 0; m < 4; ++m) { a1r[m][1] = ldA(c, m, 1); br[m][1] = ldB(c, m, 1); }
    if (T + 1 < NT_) STAGE(pB0, pB1, 16384, 1, cn);
    __builtin_amdgcn_s_setprio(1);
#pragma unroll
    for (int kk = 0; kk < 2; ++kk)
#pragma unroll
      for (int m = 0; m < 4; ++m)
#pragma unroll
        for (int n = 0; n < 2; ++n)
          acc[m][n] = MFMA(a1r[m][kk], br[n][kk], acc[m][n]);
    __builtin_amdgcn_s_setprio(0);
    BAR();

    // ---- phase 2: stage B23(T+1)->cn; Q1; BAR ----
    if (T + 1 < NT_) STAGE(pB2, pB3, 24576, 1, cn);
    __builtin_amdgcn_s_setprio(1);
#pragma unroll
    for (int kk = 0; kk < 2; ++kk)
#pragma unroll
      for (int m = 0; m < 4; ++m)
#pragma unroll
        for (int n = 2; n < 4; ++n)
          acc[m][n] = MFMA(a1r[m][kk], br[n][kk], acc[m][n]);
    __builtin_amdgcn_s_setprio(0);
    BAR();

    // ---- phase 3: reads a2(8); stage A23(T+1)->cn; Q2; BAR ----
#pragma unroll
    for (int m = 0; m < 4; ++m) { a2r[m][0] = ldA(c, m + 4, 0); a2r[m][1] = ldA(c, m + 4, 1); }
    if (T + 1 < NT_) STAGE(pA2, pA3, 8192, 1, cn);
    __builtin_amdgcn_s_setprio(1);
#pragma unroll
    for (int kk = 0; kk < 2; ++kk)
#pragma unroll
      for (int m = 0; m < 4; ++m)
#pragma unroll
        for (int n = 0; n < 2; ++n)
          acc[m + 4][n] = MFMA(a2r[m][kk], br[n][kk], acc[m + 4][n]);
    __builtin_amdgcn_s_setprio(0);
    BAR();

    // ---- phase 4: stage A01(T+2)->c; Q3; VM2; BAR ----
    if (T + 2 < NT_) STAGE(pA0, pA1, 0, 2, c);
    __builtin_amdgcn_s_setprio(1);
#pragma unroll
    for (int kk = 0; kk < 2; ++kk)
#pragma unroll
      for (int m = 0; m < 4; ++m)
#pragma unroll
        for (int n = 2; n < 4; ++n)
          acc[m + 4][n] = MFMA(a2r[m][kk], br[n][kk], acc[m + 4][n]);
    __builtin_amdgcn_s_setprio(0);
    if (T < NT_ - 2) { VM2(); } else { VM0(); }
    BAR();

    pA0 += 64; pA1 += 64; pA2 += 64; pA3 += 64;
    pB0 += 64; pB1 += 64; pB2 += 64; pB3 += 64;
  }
#undef STAGE

  // epilogue: C/D layout col=lane&15, row=(lane>>4)*4+j (m89/m91)
  const int orow = (lane >> 4) * 4, ocol = lane & 15;
  const int rbase = row0 + mi * 256 + wm * 128;
  const int cbase = ni * 256 + wn * 64;
#pragma unroll
  for (int m = 0; m < 8; ++m)
#pragma unroll
    for (int n = 0; n < 4; ++n)
#pragma unroll
      for (int j = 0; j < 4; ++j)
        C[(size_t)(rbase + m * 16 + orow + j) * NOUT + (cbase + n * 16 + ocol)] =
            acc[m][n][j];
}

// ============================================================
extern "C" void kernel_launch(void* const* d_in, const int* in_sizes, int n_in,
                              void* d_out, int out_size, void* d_ws, size_t ws_size,
                              hipStream_t stream) {
  const float* x    = (const float*)d_in[0];
  const float* Wenc = (const float*)d_in[1];
  const float* Wdec = (const float*)d_in[2];
  const float* Wout = (const float*)d_in[3];
  float* out = (float*)d_out;

  char* ws = (char*)d_ws;
  bf16*  Wb = (bf16*)ws;                          // 8 MiB
  float* z  = (float*)(ws + 8388608);             // 1 MiB
  bf16*  h  = (bf16*)(ws + 8388608 + 1048576);    // up to 256 MiB

  const size_t head = 8388608 + 1048576;
  const size_t avail = ws_size > head ? ws_size - head : 0;
  int nch = 1;
  while (nch < 128 && (size_t)(MROWS / nch) * FFN_ * 2 > avail) nch <<= 1;
  const int chunk = MROWS / nch;   // multiple of 256

  k_encode<<<1024, 256, 0, stream>>>(x, Wenc, z, Wout, Wb);
  for (int c = 0; c < nch; ++c) {
    const int row0 = c * chunk;
    dim3 hg(chunk / 64, 2);
    k_hgen<<<hg, 256, 0, stream>>>(z, Wdec, h, row0);
    k_gemm8<<<(chunk / 256) * 4, 512, 0, stream>>>(h, Wb, out, row0);
  }
}